// Round 9
// baseline (274.539 us; speedup 1.0000x reference)
//
#include <hip/hip_runtime.h>
#include <hip/hip_bf16.h>
#include <math.h>

// Problem constants (img 2048x2048, strides 4..64, 3 anchors/loc)
#define K_TOP 1000
#define NLEV  5
#define NSEL  5000          // 5 * 1000 candidates
#define NSLOT 5120          // 5 * 1024 slots (1024 stride per level)
#define NCH   79            // ceil(5000/64) chunks of 64 candidates
#define NP    5000          // u64 row stride of transposed mask: maskT[w*NP + i]
#define NW    80            // allocated word-rows (0..78 used)
#define ATOT  1047552
#define BBOX_CLIP_F 4.135166556742356f

// ws layout in u32 units
#define INFO1   0          // 5*4: [binstar, above, need, pad]
#define CANDCNT 32         // 5 (own 128B line)
#define EQCNT   64         // 5
#define MAXC    96         // 1 (float bits)
#define DONEC   128        // 5 (hist completion counters)
#define HIST1   256        // 5*2048 -> ends 10496
#define CANDO   10496      // 5*1024 per-level local indices -> 15616
#define EQO     15616      // u64[5*4096] = 40960 u32 -> 56576 (byte 62464 %8==0)
#define KEYS2   56576      // u64[5000] = 10000 u32 -> 66576 (byte 226304 %8==0)
#define SORTCP  66576      // u32[5120] -> 71696
#define BOXA    71696      // f32[5120][4] -> 92176
#define VALIDA  92176      // u32[5120] -> 97296
#define NBSO    97296      // f32[5120][4] -> 117776
#define AREAS   117776     // f32[5120] -> 122896
#define VALSB   122896     // u32[160] 5000-bit valid mask (byte 491584 %8==0)
#define MASKO   124080     // u64[NW*NP] (byte 496320 %16==0) -> ends 924080 u32

__device__ __forceinline__ int loff(int l){
  return (l==0)?0:(l==1)?786432:(l==2)?983040:(l==3)?1032192:1044480;
}
__device__ __forceinline__ int lsize(int l){
  return (l==0)?786432:(l==1)?196608:(l==2)?49152:(l==3)?12288:3072;
}
// monotonic uint32 key: larger float <-> larger key
__device__ __forceinline__ unsigned fmono(float x){
  unsigned b=__float_as_uint(x);
  return (b&0x80000000u)? ~b : (b|0x80000000u);
}

template<typename T>
__device__ void bitonic_sort(T* sk, int n, int tid, int nth){
  for (int size=2; size<=n; size<<=1){
    for (int stride=size>>1; stride>0; stride>>=1){
      __syncthreads();
      for (int p=tid; p<(n>>1); p+=nth){
        int lo = ((p/stride)*stride<<1) + (p%stride);
        int hi = lo+stride;
        bool asc = ((lo & size)==0);
        T a=sk[lo], b=sk[hi];
        if ((a>b)==asc){ sk[lo]=b; sk[hi]=a; }
      }
    }
  }
  __syncthreads();
}

__global__ void k_init(unsigned* ws32){
  int t=blockIdx.x*blockDim.x+threadIdx.x;
  if (t<10496) ws32[t]=0u;
  else if (t<10656) ws32[VALSB + (t-10496)]=0u;
}

// pass-1 histogram (bits 31..21) with match-any wave aggregation (hot-bin safe)
// + fused last-block descending scan -> INFO1
__global__ void k_hist1(const float* __restrict__ obj, unsigned* ws32){
  int l = blockIdx.y;
  int n = lsize(l), off = loff(l);
  unsigned* hist = ws32 + HIST1 + l*2048;
  int lane = threadIdx.x & 63;
  __shared__ unsigned h[2048];
  for (int t=threadIdx.x; t<2048; t+=blockDim.x) h[t]=0u;
  __syncthreads();
  // wave-uniform trip count: n, blockDim, grid stride all multiples of 64
  for (int i = blockIdx.x*blockDim.x + threadIdx.x; i<n; i += gridDim.x*blockDim.x){
    unsigned bin = fmono(obj[off+i])>>21;
    unsigned long long todo = ~0ULL;
    while (todo){
      int src = __ffsll((unsigned long long)todo) - 1;
      unsigned b = (unsigned)__shfl((int)bin, src, 64);
      unsigned long long m = __ballot(bin==b);
      if (lane==src) atomicAdd(&h[b], (unsigned)__popcll(m));
      todo &= ~m;
    }
  }
  __syncthreads();
  for (int t=threadIdx.x; t<2048; t+=blockDim.x){
    unsigned v=h[t];
    if (v) atomicAdd(&hist[t], v);
  }
  // last-block election
  __shared__ unsigned isLast;
  __threadfence();
  if (threadIdx.x==0){
    unsigned old = atomicAdd(&ws32[DONEC+l],1u);
    isLast = (old == gridDim.x-1u) ? 1u : 0u;
  }
  __syncthreads();
  if (!isLast) return;
  __threadfence();
  for (int t=threadIdx.x; t<2048; t+=blockDim.x) h[t] = atomicAdd(&hist[t],0u);
  __syncthreads();
  int tid=threadIdx.x;
  __shared__ unsigned psum[256];
  unsigned local=0;
  for (int r=tid*8; r<tid*8+8; r++) local += h[2047-r];
  psum[tid]=local; __syncthreads();
  for (int s=1;s<256;s<<=1){
    unsigned v=(tid>=s)?psum[tid-s]:0u;
    __syncthreads();
    psum[tid]+=v;
    __syncthreads();
  }
  unsigned excl=(tid==0)?0u:psum[tid-1];
  if (excl < K_TOP && psum[tid] >= K_TOP){
    unsigned cum=excl;
    for (int r=tid*8; r<tid*8+8; r++){
      unsigned hv=h[2047-r];
      if (cum+hv >= K_TOP){
        ws32[INFO1+l*4+0]=(unsigned)(2047-r); // boundary bin b*
        ws32[INFO1+l*4+1]=cum;                // count in strictly greater bins
        ws32[INFO1+l*4+2]=K_TOP-cum;          // needed from bin b*
        break;
      }
      cum+=hv;
    }
  }
}

// single full scan: greater-bin -> CANDO (all top-k), boundary-bin -> EQO (u64 sort keys)
// wave-aggregated appends; level bounds & ATOT are multiples of 64 so waves never straddle.
__global__ void k_collect(const float* __restrict__ obj, unsigned* ws32){
  unsigned b0=ws32[INFO1+0], b1=ws32[INFO1+4], b2=ws32[INFO1+8],
           b3=ws32[INFO1+12], b4=ws32[INFO1+16];
  int lane = threadIdx.x & 63;
  unsigned long long lmask = (lane==0)?0ULL:(~0ULL >> (64-lane));
  unsigned long long* eq64 = (unsigned long long*)(ws32+EQO);
  for (int g = blockIdx.x*blockDim.x + threadIdx.x; g<ATOT; g += gridDim.x*blockDim.x){
    int l = (g<786432)?0:(g<983040)?1:(g<1032192)?2:(g<1044480)?3:4;
    unsigned bstar = (l==0)?b0:(l==1)?b1:(l==2)?b2:(l==3)?b3:b4;
    unsigned key = fmono(obj[g]);
    unsigned bin = key>>21;
    bool isc = bin>bstar, ise = bin==bstar;
    unsigned long long mc = __ballot(isc);
    unsigned long long me = __ballot(ise);
    if (mc){
      unsigned base=0;
      if (lane==0) base = atomicAdd(&ws32[CANDCNT+l], (unsigned)__popcll(mc));
      base = __shfl(base, 0, 64);
      if (isc){
        unsigned p = base + (unsigned)__popcll(mc & lmask);
        if (p<1024u) ws32[CANDO + l*1024 + p] = (unsigned)(g - loff(l));
      }
    }
    if (me){
      unsigned base=0;
      if (lane==0) base = atomicAdd(&ws32[EQCNT+l], (unsigned)__popcll(me));
      base = __shfl(base, 0, 64);
      if (ise){
        unsigned p = base + (unsigned)__popcll(me & lmask);
        unsigned idx = (unsigned)(g - loff(l));
        if (p<4096u) eq64[(size_t)l*4096 + p] = (((unsigned long long)(~key))<<20) | idx;
      }
    }
  }
}

// fused per-level: (A) sort boundary bin by (score desc, idx asc), take `need` best (exact
// top_k ties); (B) full-level sort -> concat order; decode+clip+valid; sigmoid key;
// stable partition (valid then invalid == per-level key-ascending) -> KEYS2
__global__ void k_tailfuse(const float* __restrict__ obj, const float* __restrict__ deltas,
                           const float* __restrict__ anchors, unsigned* ws32){
  int l = blockIdx.x, t = threadIdx.x;   // 1024 threads
  __shared__ unsigned long long sbuf[4096]; // 32 KiB (phase A sort; phase B reuses [0..1023])
  __shared__ unsigned pfx[1024];
  __shared__ unsigned nv;
  int off = loff(l);
  // ---- phase A: boundary-bin tail ----
  unsigned cnt = ws32[EQCNT+l]; if (cnt>4096u) cnt=4096u;
  unsigned base = ws32[CANDCNT+l];
  const unsigned long long* eq = (const unsigned long long*)(ws32+EQO) + (size_t)l*4096;
  for (int i=t;i<4096;i+=1024) sbuf[i] = (i<(int)cnt)? eq[i] : ~0ULL;
  __syncthreads();
  bitonic_sort<unsigned long long>(sbuf, 4096, t, 1024);
  // sorted tail now in sbuf[0..need); selected head (greater bins) in CANDO[0..base)
  unsigned idx_t = 0xFFFFFFFFu;
  if (t < K_TOP)
    idx_t = (t < (int)base)? ws32[CANDO + l*1024 + t]
                           : (unsigned)(sbuf[t-(int)base] & 0xFFFFFu);
  __syncthreads();   // done reading sbuf tail before reuse
  // ---- phase B: level sort by (score desc, idx asc) ----
  if (t<K_TOP){
    unsigned m = ~fmono(obj[off+idx_t]);
    sbuf[t] = ((unsigned long long)m<<20) | idx_t;
  } else sbuf[t] = ~0ULL;
  __syncthreads();
  bitonic_sort<unsigned long long>(sbuf, 1024, t, 1024);
  // t is now the concat position j within the level
  unsigned valid=0u;
  unsigned long long key64=~0ULL;
  int s = (l<<10)|t;
  if (t<K_TOP){
    unsigned idx = (unsigned)(sbuf[t] & 0xFFFFFu);
    int g = off + (int)idx;
    float o = obj[g];
    const float* dd = deltas + 4*(size_t)g;
    const float* aa = anchors + 4*(size_t)g;
    float dx=dd[0], dy=dd[1], dw=dd[2], dh=dd[3];
    float a0=aa[0], a1=aa[1], a2=aa[2], a3=aa[3];
    float w = __fsub_rn(a2,a0), h = __fsub_rn(a3,a1);
    float cx = __fadd_rn(a0, __fmul_rn(0.5f,w));
    float cy = __fadd_rn(a1, __fmul_rn(0.5f,h));
    float dwc = fminf(dw, BBOX_CLIP_F);
    float dhc = fminf(dh, BBOX_CLIP_F);
    float pcx = __fadd_rn(__fmul_rn(dx,w), cx);
    float pcy = __fadd_rn(__fmul_rn(dy,h), cy);
    float pw = __fmul_rn((float)exp((double)dwc), w);
    float ph = __fmul_rn((float)exp((double)dhc), h);
    float x1 = __fsub_rn(pcx, __fmul_rn(0.5f,pw));
    float y1 = __fsub_rn(pcy, __fmul_rn(0.5f,ph));
    float x2 = __fadd_rn(pcx, __fmul_rn(0.5f,pw));
    float y2 = __fadd_rn(pcy, __fmul_rn(0.5f,ph));
    float x1c=fminf(fmaxf(x1,0.0f),2048.0f);
    float y1c=fminf(fmaxf(y1,0.0f),2048.0f);
    float x2c=fminf(fmaxf(x2,0.0f),2048.0f);
    float y2c=fminf(fmaxf(y2,0.0f),2048.0f);
    bool v = (__fsub_rn(x2c,x1c)>=0.001f) && (__fsub_rn(y2c,y1c)>=0.001f);
    float* bx = (float*)(ws32+BOXA) + 4*s;
    bx[0]=x1c; bx[1]=y1c; bx[2]=x2c; bx[3]=y2c;
    ws32[VALIDA+s] = v?1u:0u;
    valid = v?1u:0u;
    double sg = 1.0/(1.0+exp(-(double)o));
    float sc = (float)sg;
    if (sc < 0.0f) valid = 0u;
    float masked = valid? sc : -1.0f;
    unsigned sm = ~fmono(masked);
    unsigned cp = (unsigned)(l*K_TOP + t);
    key64 = ((unsigned long long)sm<<13) | cp;
    float mx = fmaxf(fmaxf(x1c,y1c),fmaxf(x2c,y2c));
    atomicMax(&ws32[MAXC], __float_as_uint(mx));
  }
  // stable partition: valid block (j order) then invalid block (j order) == key-ascending
  pfx[t] = (t<K_TOP)? valid : 0u;
  __syncthreads();
  for (int st=1; st<1024; st<<=1){
    unsigned x = (t>=st)? pfx[t-st]:0u;
    __syncthreads();
    pfx[t]+=x;
    __syncthreads();
  }
  if (t==1023) nv = pfx[1023];
  __syncthreads();
  if (t<K_TOP){
    unsigned inc = pfx[t];
    unsigned pos = valid? (inc-1u) : (nv + (unsigned)t - inc);
    ((unsigned long long*)(ws32+KEYS2))[l*K_TOP + pos] = key64;
  }
}

// fused 5-way merge by rank + prep: grank via 4 binary searches (keys unique by cp),
// then write NBSO/AREAS/SORTCP/VALSB directly at the sorted position.
__global__ void k_mergeprep(unsigned* ws32){
  int l = blockIdx.x, t = threadIdx.x;  // 5 blocks x 1024
  const unsigned long long* k2 = (const unsigned long long*)(ws32+KEYS2);
  __shared__ unsigned long long sk[NLEV][K_TOP];   // 40000 B
  for (int m=0;m<NLEV;m++)
    if (t<K_TOP) sk[m][t] = k2[m*K_TOP+t];
  __syncthreads();
  if (t>=K_TOP) return;
  unsigned long long key = sk[l][t];
  int grank = t;
  #pragma unroll
  for (int m=0;m<NLEV;m++){
    if (m==l) continue;
    int lo=0, hi=K_TOP;
    while (lo<hi){ int mid=(lo+hi)>>1; if (sk[m][mid]<key) lo=mid+1; else hi=mid; }
    grank += lo;
  }
  unsigned cp = (unsigned)(key & 0x1FFFULL);
  int j = (int)cp - l*K_TOP;
  int s = (l<<10)|j;
  const float* bx = (const float*)(ws32+BOXA) + 4*s;
  float mc = __uint_as_float(ws32[MAXC]);
  float offv = __fmul_rn((float)l, __fadd_rn(mc,1.0f));
  float n0=__fadd_rn(bx[0],offv), n1=__fadd_rn(bx[1],offv);
  float n2=__fadd_rn(bx[2],offv), n3=__fadd_rn(bx[3],offv);
  float* nb = (float*)(ws32+NBSO) + 4*grank;
  nb[0]=n0; nb[1]=n1; nb[2]=n2; nb[3]=n3;
  ((float*)(ws32+AREAS))[grank] = __fmul_rn(__fsub_rn(n2,n0), __fsub_rn(n3,n1));
  ws32[SORTCP+grank] = cp;
  if (ws32[VALIDA+s]) atomicOr(&ws32[VALSB + (grank>>5)], 1u<<(grank&31));
}

// transposed suppression mask, LOWER TRIANGLE only (k_nms reads w <= chunk(i)):
// maskT[w*NP + i] bit b = IoU(i, 64w+b) > 0.7
__global__ void k_mask(unsigned* ws32){
  if (blockIdx.y > blockIdx.x) return;   // w > chunk(i): never read
  int i = blockIdx.x*64 + threadIdx.x;
  int w = blockIdx.y;
  if (i >= NSEL) return;
  const float* nbS = (const float*)(ws32+NBSO);
  const float* areaS = (const float*)(ws32+AREAS);
  unsigned long long* maskT = (unsigned long long*)(ws32+MASKO);
  float bx1=nbS[4*i], by1=nbS[4*i+1], bx2=nbS[4*i+2], by2=nbS[4*i+3];
  float ai=areaS[i];
  unsigned long long word=0ULL;
  int jbase=w*64;
  int jend = jbase+64; if (jend>NSEL) jend=NSEL;
  for (int j=jbase; j<jend; ++j){
    float iw = fmaxf(__fsub_rn(fminf(nbS[4*j+2],bx2), fmaxf(nbS[4*j+0],bx1)),0.0f);
    float ih = fmaxf(__fsub_rn(fminf(nbS[4*j+3],by2), fmaxf(nbS[4*j+1],by1)),0.0f);
    float inter=__fmul_rn(iw,ih);
    float iou=__fdiv_rn(inter, __fsub_rn(__fadd_rn(areaS[j],ai),inter));
    if (iou>0.7f) word |= (1ULL<<(j-jbase));
  }
  maskT[(size_t)w*NP + i]=word;
}

// chunk-64 gather NMS with early exit at rank>=1000 + fused output gather.
// Kept positions tracked in LDS; single wave; all branches wave-uniform where needed.
__global__ void __launch_bounds__(64) k_nms(const unsigned* __restrict__ ws32,
                                            float* __restrict__ out){
  const unsigned long long* maskT = (const unsigned long long*)(ws32+MASKO);
  const unsigned long long* validw = (const unsigned long long*)(ws32+VALSB);
  int lane = threadIdx.x;
  __shared__ unsigned long long Kb[NW];   // kept word per finished chunk
  __shared__ unsigned long long Vb[NW];   // valid words
  __shared__ unsigned ordl[K_TOP];        // kept sorted-positions (LDS)
  if (lane < NCH) Vb[lane] = validw[lane];
  __syncthreads();
  unsigned long long lower = (lane==0)?0ULL:(~0ULL >> (64-lane));
  int rank=0;
  for (int c=0;c<NCH;c++){
    int q = (c<<6) + lane;
    size_t qc = (q < NSEL)? (size_t)q : (size_t)(NSEL-1);  // clamped lanes have valid=0, never kept
    unsigned long long sup=0ULL;
    #pragma unroll 8
    for (int w=0; w<c; ++w)
      sup |= maskT[(size_t)w*NP + qc] & Kb[w];
    unsigned long long intra = maskT[(size_t)c*NP + qc];
    unsigned long long valc  = Vb[c];
    bool al = ((valc>>lane)&1ULL) && (sup==0ULL);
    unsigned long long nd = intra & lower;   // smaller-index in-chunk suppressors
    unsigned long long kept = __ballot(al);
    for (int it=0; it<96; ++it){
      bool s2 = (kept & nd) != 0ULL;
      unsigned long long nk = __ballot(al && !s2);
      if (nk==kept) break;
      kept = nk;
    }
    if ((kept>>lane)&1ULL){
      int pos = rank + (int)__popcll(kept & lower);
      if (pos < K_TOP) ordl[pos] = (unsigned)q;
    }
    rank += (int)__popcll(kept);
    if (rank >= K_TOP) break;   // exact: rank>=1000 kept are dropped by ref
    if (lane==0) Kb[c] = kept;
    __syncthreads();
  }
  __syncthreads();
  int cnt = (rank>K_TOP)?K_TOP:rank;
  for (int r=lane; r<K_TOP; r+=64){
    float4 v = make_float4(0.f,0.f,0.f,0.f);
    if (r < cnt){
      unsigned cp = ws32[SORTCP + ordl[r]];
      int l = cp/1000, j = cp - l*1000;
      int s = (l<<10)|j;
      const float* b = (const float*)(ws32+BOXA) + 4*s;
      v = make_float4(b[0],b[1],b[2],b[3]);
    }
    ((float4*)out)[r] = v;
  }
}

extern "C" void kernel_launch(void* const* d_in, const int* in_sizes, int n_in,
                              void* d_out, int out_size, void* d_ws, size_t ws_size,
                              hipStream_t stream){
  const float* obj     = (const float*)d_in[0];
  const float* deltas  = (const float*)d_in[1];
  const float* anchors = (const float*)d_in[2];
  unsigned* ws32 = (unsigned*)d_ws;
  float* out = (float*)d_out;
  (void)in_sizes; (void)n_in; (void)out_size; (void)ws_size;

  hipLaunchKernelGGL(k_init,      dim3(42),      dim3(256), 0, stream, ws32);
  hipLaunchKernelGGL(k_hist1,     dim3(104,5),   dim3(256), 0, stream, obj, ws32);
  hipLaunchKernelGGL(k_collect,   dim3(512),     dim3(256), 0, stream, obj, ws32);
  hipLaunchKernelGGL(k_tailfuse,  dim3(5),       dim3(1024),0, stream, obj, deltas, anchors, ws32);
  hipLaunchKernelGGL(k_mergeprep, dim3(5),       dim3(1024),0, stream, ws32);
  hipLaunchKernelGGL(k_mask,      dim3(79,79),   dim3(64),  0, stream, ws32);
  hipLaunchKernelGGL(k_nms,       dim3(1),       dim3(64),  0, stream, ws32, out);
}

// Round 10
// 215.424 us; speedup vs baseline: 1.2744x; 1.2744x over previous
//
#include <hip/hip_runtime.h>
#include <hip/hip_bf16.h>
#include <math.h>

// Problem constants (img 2048x2048, strides 4..64, 3 anchors/loc)
#define K_TOP 1000
#define NLEV  5
#define NSEL  5000          // 5 * 1000 candidates
#define NSLOT 5120          // 5 * 1024 slots (1024 stride per level)
#define NCH   79            // ceil(5000/64) chunks of 64 candidates
#define NP    5000          // u64 row stride of transposed mask: maskT[w*NP + i]
#define NW    80            // allocated word-rows (0..78 used)
#define ATOT  1047552
#define BBOX_CLIP_F 4.135166556742356f

// ws layout in u32 units
#define INFO1   0          // 5*4: [binstar, above, need, pad]
#define CANDCNT 32         // 5 (own 128B line)
#define EQCNT   64         // 5
#define MAXC    96         // 1 (float bits)
#define DONEC   128        // 5 (hist completion counters)
#define HIST1   256        // 5*2048 -> ends 10496
#define CANDO   10496      // 5*1024 per-level local indices -> 15616
#define EQO     15616      // u64[5*4096] = 40960 u32 -> 56576 (byte 62464 %8==0)
#define KEYS2   56576      // u64[5000] = 10000 u32 -> 66576 (byte 226304 %8==0)
#define SORTCP  66576      // u32[5120] -> 71696
#define BOXA    71696      // f32[5120][4] -> 92176
#define VALIDA  92176      // u32[5120] -> 97296
#define NBSO    97296      // f32[5120][4] -> 117776
#define AREAS   117776     // f32[5120] -> 122896
#define VALSB   122896     // u32[160] 5000-bit valid mask (byte 491584 %8==0)
#define MASKO   124080     // u64[NW*NP] (byte 496320 %16==0) -> ends 924080 u32

__device__ __forceinline__ int loff(int l){
  return (l==0)?0:(l==1)?786432:(l==2)?983040:(l==3)?1032192:1044480;
}
// monotonic uint32 key: larger float <-> larger key
__device__ __forceinline__ unsigned fmono(float x){
  unsigned b=__float_as_uint(x);
  return (b&0x80000000u)? ~b : (b|0x80000000u);
}

template<typename T>
__device__ void bitonic_sort(T* sk, int n, int tid, int nth){
  for (int size=2; size<=n; size<<=1){
    for (int stride=size>>1; stride>0; stride>>=1){
      __syncthreads();
      for (int p=tid; p<(n>>1); p+=nth){
        int lo = ((p/stride)*stride<<1) + (p%stride);
        int hi = lo+stride;
        bool asc = ((lo & size)==0);
        T a=sk[lo], b=sk[hi];
        if ((a>b)==asc){ sk[lo]=b; sk[hi]=a; }
      }
    }
  }
  __syncthreads();
}

__global__ void k_init(unsigned* ws32){
  int t=blockIdx.x*blockDim.x+threadIdx.x;
  if (t<10496) ws32[t]=0u;
  else if (t<10656) ws32[VALSB + (t-10496)]=0u;
}

// pass-1 histogram (bits 31..21): flat 512-block grid (2048 contiguous elems/block,
// each block inside ONE level since level bounds are multiples of 2048), float4 loads,
// 8x replicated LDS hist (hot-bin serialization 64-way -> 8-way, spread across banks).
// + per-level last-block descending scan -> INFO1.
__global__ void k_hist1(const float* __restrict__ obj, unsigned* ws32){
  int b = blockIdx.x;                 // 512 blocks
  int l = (b<384)?0:(b<480)?1:(b<504)?2:(b<510)?3:4;
  unsigned* hist = ws32 + HIST1 + l*2048;
  int t = threadIdx.x;                // 256
  int rep = t & 7;
  __shared__ unsigned h[2048*8];      // 64 KiB replicated hist
  for (int i=t; i<2048*8; i+=256) h[i]=0u;
  __syncthreads();
  const float4* src = (const float4*)(obj + (size_t)b*2048);
  int nVec = (b==511)? 256 : 512;     // tail block has 1024 elems
  for (int i=t; i<nVec; i+=256){
    float4 v = src[i];
    atomicAdd(&h[(fmono(v.x)>>21)*8 + rep], 1u);
    atomicAdd(&h[(fmono(v.y)>>21)*8 + rep], 1u);
    atomicAdd(&h[(fmono(v.z)>>21)*8 + rep], 1u);
    atomicAdd(&h[(fmono(v.w)>>21)*8 + rep], 1u);
  }
  __syncthreads();
  for (int bin=t; bin<2048; bin+=256){
    unsigned v=0;
    #pragma unroll
    for (int r=0;r<8;r++) v += h[bin*8+r];
    if (v) atomicAdd(&hist[bin], v);
  }
  // per-level last-block election
  __shared__ unsigned isLast;
  __threadfence();
  if (t==0){
    unsigned nb = (l==0)?384u:(l==1)?96u:(l==2)?24u:(l==3)?6u:2u;
    unsigned old = atomicAdd(&ws32[DONEC+l],1u);
    isLast = (old == nb-1u) ? 1u : 0u;
  }
  __syncthreads();
  if (!isLast) return;
  __threadfence();
  for (int i=t; i<2048; i+=256) h[i] = atomicAdd(&hist[i],0u);  // coherent re-read
  __syncthreads();
  __shared__ unsigned psum[256];
  unsigned local=0;
  for (int r=t*8; r<t*8+8; r++) local += h[2047-r];
  psum[t]=local; __syncthreads();
  for (int s=1;s<256;s<<=1){
    unsigned v=(t>=s)?psum[t-s]:0u;
    __syncthreads();
    psum[t]+=v;
    __syncthreads();
  }
  unsigned excl=(t==0)?0u:psum[t-1];
  if (excl < K_TOP && psum[t] >= K_TOP){
    unsigned cum=excl;
    for (int r=t*8; r<t*8+8; r++){
      unsigned hv=h[2047-r];
      if (cum+hv >= K_TOP){
        ws32[INFO1+l*4+0]=(unsigned)(2047-r); // boundary bin b*
        ws32[INFO1+l*4+1]=cum;                // count in strictly greater bins
        ws32[INFO1+l*4+2]=K_TOP-cum;          // needed from bin b*
        break;
      }
      cum+=hv;
    }
  }
}

// single full scan: greater-bin -> CANDO (all top-k), boundary-bin -> EQO (u64 sort keys)
// wave-aggregated appends; level bounds & ATOT are multiples of 64 so waves never straddle.
__global__ void k_collect(const float* __restrict__ obj, unsigned* ws32){
  unsigned b0=ws32[INFO1+0], b1=ws32[INFO1+4], b2=ws32[INFO1+8],
           b3=ws32[INFO1+12], b4=ws32[INFO1+16];
  int lane = threadIdx.x & 63;
  unsigned long long lmask = (lane==0)?0ULL:(~0ULL >> (64-lane));
  unsigned long long* eq64 = (unsigned long long*)(ws32+EQO);
  for (int g = blockIdx.x*blockDim.x + threadIdx.x; g<ATOT; g += gridDim.x*blockDim.x){
    int l = (g<786432)?0:(g<983040)?1:(g<1032192)?2:(g<1044480)?3:4;
    unsigned bstar = (l==0)?b0:(l==1)?b1:(l==2)?b2:(l==3)?b3:b4;
    unsigned key = fmono(obj[g]);
    unsigned bin = key>>21;
    bool isc = bin>bstar, ise = bin==bstar;
    unsigned long long mc = __ballot(isc);
    unsigned long long me = __ballot(ise);
    if (mc){
      unsigned base=0;
      if (lane==0) base = atomicAdd(&ws32[CANDCNT+l], (unsigned)__popcll(mc));
      base = __shfl(base, 0, 64);
      if (isc){
        unsigned p = base + (unsigned)__popcll(mc & lmask);
        if (p<1024u) ws32[CANDO + l*1024 + p] = (unsigned)(g - loff(l));
      }
    }
    if (me){
      unsigned base=0;
      if (lane==0) base = atomicAdd(&ws32[EQCNT+l], (unsigned)__popcll(me));
      base = __shfl(base, 0, 64);
      if (ise){
        unsigned p = base + (unsigned)__popcll(me & lmask);
        unsigned idx = (unsigned)(g - loff(l));
        if (p<4096u) eq64[(size_t)l*4096 + p] = (((unsigned long long)(~key))<<20) | idx;
      }
    }
  }
}

// fused per-level: (A) sort boundary bin by (score desc, idx asc), take `need` best (exact
// top_k ties); (B) full-level sort -> concat order; decode+clip+valid; sigmoid key;
// stable partition (valid then invalid == per-level key-ascending) -> KEYS2
__global__ void k_tailfuse(const float* __restrict__ obj, const float* __restrict__ deltas,
                           const float* __restrict__ anchors, unsigned* ws32){
  int l = blockIdx.x, t = threadIdx.x;   // 1024 threads
  __shared__ unsigned long long sbuf[4096]; // 32 KiB (phase A sort; phase B reuses [0..1023])
  __shared__ unsigned pfx[1024];
  __shared__ unsigned nv;
  int off = loff(l);
  // ---- phase A: boundary-bin tail ----
  unsigned cnt = ws32[EQCNT+l]; if (cnt>4096u) cnt=4096u;
  unsigned base = ws32[CANDCNT+l];
  const unsigned long long* eq = (const unsigned long long*)(ws32+EQO) + (size_t)l*4096;
  for (int i=t;i<4096;i+=1024) sbuf[i] = (i<(int)cnt)? eq[i] : ~0ULL;
  __syncthreads();
  bitonic_sort<unsigned long long>(sbuf, 4096, t, 1024);
  // sorted tail now in sbuf[0..need); selected head (greater bins) in CANDO[0..base)
  unsigned idx_t = 0xFFFFFFFFu;
  if (t < K_TOP)
    idx_t = (t < (int)base)? ws32[CANDO + l*1024 + t]
                           : (unsigned)(sbuf[t-(int)base] & 0xFFFFFu);
  __syncthreads();   // done reading sbuf tail before reuse
  // ---- phase B: level sort by (score desc, idx asc) ----
  if (t<K_TOP){
    unsigned m = ~fmono(obj[off+idx_t]);
    sbuf[t] = ((unsigned long long)m<<20) | idx_t;
  } else sbuf[t] = ~0ULL;
  __syncthreads();
  bitonic_sort<unsigned long long>(sbuf, 1024, t, 1024);
  // t is now the concat position j within the level
  unsigned valid=0u;
  unsigned long long key64=~0ULL;
  int s = (l<<10)|t;
  if (t<K_TOP){
    unsigned idx = (unsigned)(sbuf[t] & 0xFFFFFu);
    int g = off + (int)idx;
    float o = obj[g];
    const float* dd = deltas + 4*(size_t)g;
    const float* aa = anchors + 4*(size_t)g;
    float dx=dd[0], dy=dd[1], dw=dd[2], dh=dd[3];
    float a0=aa[0], a1=aa[1], a2=aa[2], a3=aa[3];
    float w = __fsub_rn(a2,a0), h = __fsub_rn(a3,a1);
    float cx = __fadd_rn(a0, __fmul_rn(0.5f,w));
    float cy = __fadd_rn(a1, __fmul_rn(0.5f,h));
    float dwc = fminf(dw, BBOX_CLIP_F);
    float dhc = fminf(dh, BBOX_CLIP_F);
    float pcx = __fadd_rn(__fmul_rn(dx,w), cx);
    float pcy = __fadd_rn(__fmul_rn(dy,h), cy);
    float pw = __fmul_rn((float)exp((double)dwc), w);
    float ph = __fmul_rn((float)exp((double)dhc), h);
    float x1 = __fsub_rn(pcx, __fmul_rn(0.5f,pw));
    float y1 = __fsub_rn(pcy, __fmul_rn(0.5f,ph));
    float x2 = __fadd_rn(pcx, __fmul_rn(0.5f,pw));
    float y2 = __fadd_rn(pcy, __fmul_rn(0.5f,ph));
    float x1c=fminf(fmaxf(x1,0.0f),2048.0f);
    float y1c=fminf(fmaxf(y1,0.0f),2048.0f);
    float x2c=fminf(fmaxf(x2,0.0f),2048.0f);
    float y2c=fminf(fmaxf(y2,0.0f),2048.0f);
    bool v = (__fsub_rn(x2c,x1c)>=0.001f) && (__fsub_rn(y2c,y1c)>=0.001f);
    float* bx = (float*)(ws32+BOXA) + 4*s;
    bx[0]=x1c; bx[1]=y1c; bx[2]=x2c; bx[3]=y2c;
    ws32[VALIDA+s] = v?1u:0u;
    valid = v?1u:0u;
    double sg = 1.0/(1.0+exp(-(double)o));
    float sc = (float)sg;
    if (sc < 0.0f) valid = 0u;
    float masked = valid? sc : -1.0f;
    unsigned sm = ~fmono(masked);
    unsigned cp = (unsigned)(l*K_TOP + t);
    key64 = ((unsigned long long)sm<<13) | cp;
    float mx = fmaxf(fmaxf(x1c,y1c),fmaxf(x2c,y2c));
    atomicMax(&ws32[MAXC], __float_as_uint(mx));
  }
  // stable partition: valid block (j order) then invalid block (j order) == key-ascending
  pfx[t] = (t<K_TOP)? valid : 0u;
  __syncthreads();
  for (int st=1; st<1024; st<<=1){
    unsigned x = (t>=st)? pfx[t-st]:0u;
    __syncthreads();
    pfx[t]+=x;
    __syncthreads();
  }
  if (t==1023) nv = pfx[1023];
  __syncthreads();
  if (t<K_TOP){
    unsigned inc = pfx[t];
    unsigned pos = valid? (inc-1u) : (nv + (unsigned)t - inc);
    ((unsigned long long*)(ws32+KEYS2))[l*K_TOP + pos] = key64;
  }
}

// fused 5-way merge by rank + prep: grank via 4 binary searches (keys unique by cp),
// then write NBSO/AREAS/SORTCP/VALSB directly at the sorted position.
__global__ void k_mergeprep(unsigned* ws32){
  int l = blockIdx.x, t = threadIdx.x;  // 5 blocks x 1024
  const unsigned long long* k2 = (const unsigned long long*)(ws32+KEYS2);
  __shared__ unsigned long long sk[NLEV][K_TOP];   // 40000 B
  for (int m=0;m<NLEV;m++)
    if (t<K_TOP) sk[m][t] = k2[m*K_TOP+t];
  __syncthreads();
  if (t>=K_TOP) return;
  unsigned long long key = sk[l][t];
  int grank = t;
  #pragma unroll
  for (int m=0;m<NLEV;m++){
    if (m==l) continue;
    int lo=0, hi=K_TOP;
    while (lo<hi){ int mid=(lo+hi)>>1; if (sk[m][mid]<key) lo=mid+1; else hi=mid; }
    grank += lo;
  }
  unsigned cp = (unsigned)(key & 0x1FFFULL);
  int j = (int)cp - l*K_TOP;
  int s = (l<<10)|j;
  const float* bx = (const float*)(ws32+BOXA) + 4*s;
  float mc = __uint_as_float(ws32[MAXC]);
  float offv = __fmul_rn((float)l, __fadd_rn(mc,1.0f));
  float n0=__fadd_rn(bx[0],offv), n1=__fadd_rn(bx[1],offv);
  float n2=__fadd_rn(bx[2],offv), n3=__fadd_rn(bx[3],offv);
  float* nb = (float*)(ws32+NBSO) + 4*grank;
  nb[0]=n0; nb[1]=n1; nb[2]=n2; nb[3]=n3;
  ((float*)(ws32+AREAS))[grank] = __fmul_rn(__fsub_rn(n2,n0), __fsub_rn(n3,n1));
  ws32[SORTCP+grank] = cp;
  if (ws32[VALIDA+s]) atomicOr(&ws32[VALSB + (grank>>5)], 1u<<(grank&31));
}

// transposed suppression mask, LOWER TRIANGLE only (k_nms reads w <= chunk(i)):
// maskT[w*NP + i] bit b = IoU(i, 64w+b) > 0.7
__global__ void k_mask(unsigned* ws32){
  if (blockIdx.y > blockIdx.x) return;   // w > chunk(i): never read
  int i = blockIdx.x*64 + threadIdx.x;
  int w = blockIdx.y;
  if (i >= NSEL) return;
  const float* nbS = (const float*)(ws32+NBSO);
  const float* areaS = (const float*)(ws32+AREAS);
  unsigned long long* maskT = (unsigned long long*)(ws32+MASKO);
  float bx1=nbS[4*i], by1=nbS[4*i+1], bx2=nbS[4*i+2], by2=nbS[4*i+3];
  float ai=areaS[i];
  unsigned long long word=0ULL;
  int jbase=w*64;
  int jend = jbase+64; if (jend>NSEL) jend=NSEL;
  for (int j=jbase; j<jend; ++j){
    float iw = fmaxf(__fsub_rn(fminf(nbS[4*j+2],bx2), fmaxf(nbS[4*j+0],bx1)),0.0f);
    float ih = fmaxf(__fsub_rn(fminf(nbS[4*j+3],by2), fmaxf(nbS[4*j+1],by1)),0.0f);
    float inter=__fmul_rn(iw,ih);
    float iou=__fdiv_rn(inter, __fsub_rn(__fadd_rn(areaS[j],ai),inter));
    if (iou>0.7f) word |= (1ULL<<(j-jbase));
  }
  maskT[(size_t)w*NP + i]=word;
}

// chunk-64 gather NMS with early exit at rank>=1000 + fused output gather.
__global__ void __launch_bounds__(64) k_nms(const unsigned* __restrict__ ws32,
                                            float* __restrict__ out){
  const unsigned long long* maskT = (const unsigned long long*)(ws32+MASKO);
  const unsigned long long* validw = (const unsigned long long*)(ws32+VALSB);
  int lane = threadIdx.x;
  __shared__ unsigned long long Kb[NW];   // kept word per finished chunk
  __shared__ unsigned long long Vb[NW];   // valid words
  __shared__ unsigned ordl[K_TOP];        // kept sorted-positions (LDS)
  if (lane < NCH) Vb[lane] = validw[lane];
  __syncthreads();
  unsigned long long lower = (lane==0)?0ULL:(~0ULL >> (64-lane));
  int rank=0;
  for (int c=0;c<NCH;c++){
    int q = (c<<6) + lane;
    size_t qc = (q < NSEL)? (size_t)q : (size_t)(NSEL-1);  // clamped lanes have valid=0, never kept
    unsigned long long sup=0ULL;
    #pragma unroll 8
    for (int w=0; w<c; ++w)
      sup |= maskT[(size_t)w*NP + qc] & Kb[w];
    unsigned long long intra = maskT[(size_t)c*NP + qc];
    unsigned long long valc  = Vb[c];
    bool al = ((valc>>lane)&1ULL) && (sup==0ULL);
    unsigned long long nd = intra & lower;   // smaller-index in-chunk suppressors
    unsigned long long kept = __ballot(al);
    for (int it=0; it<96; ++it){
      bool s2 = (kept & nd) != 0ULL;
      unsigned long long nk = __ballot(al && !s2);
      if (nk==kept) break;
      kept = nk;
    }
    if ((kept>>lane)&1ULL){
      int pos = rank + (int)__popcll(kept & lower);
      if (pos < K_TOP) ordl[pos] = (unsigned)q;
    }
    rank += (int)__popcll(kept);
    if (rank >= K_TOP) break;   // exact: rank>=1000 kept are dropped by ref
    if (lane==0) Kb[c] = kept;
    __syncthreads();
  }
  __syncthreads();
  int cnt = (rank>K_TOP)?K_TOP:rank;
  for (int r=lane; r<K_TOP; r+=64){
    float4 v = make_float4(0.f,0.f,0.f,0.f);
    if (r < cnt){
      unsigned cp = ws32[SORTCP + ordl[r]];
      int l = cp/1000, j = cp - l*1000;
      int s = (l<<10)|j;
      const float* b = (const float*)(ws32+BOXA) + 4*s;
      v = make_float4(b[0],b[1],b[2],b[3]);
    }
    ((float4*)out)[r] = v;
  }
}

extern "C" void kernel_launch(void* const* d_in, const int* in_sizes, int n_in,
                              void* d_out, int out_size, void* d_ws, size_t ws_size,
                              hipStream_t stream){
  const float* obj     = (const float*)d_in[0];
  const float* deltas  = (const float*)d_in[1];
  const float* anchors = (const float*)d_in[2];
  unsigned* ws32 = (unsigned*)d_ws;
  float* out = (float*)d_out;
  (void)in_sizes; (void)n_in; (void)out_size; (void)ws_size;

  hipLaunchKernelGGL(k_init,      dim3(42),      dim3(256), 0, stream, ws32);
  hipLaunchKernelGGL(k_hist1,     dim3(512),     dim3(256), 0, stream, obj, ws32);
  hipLaunchKernelGGL(k_collect,   dim3(512),     dim3(256), 0, stream, obj, ws32);
  hipLaunchKernelGGL(k_tailfuse,  dim3(5),       dim3(1024),0, stream, obj, deltas, anchors, ws32);
  hipLaunchKernelGGL(k_mergeprep, dim3(5),       dim3(1024),0, stream, ws32);
  hipLaunchKernelGGL(k_mask,      dim3(79,79),   dim3(64),  0, stream, ws32);
  hipLaunchKernelGGL(k_nms,       dim3(1),       dim3(64),  0, stream, ws32, out);
}

// Round 11
// 181.323 us; speedup vs baseline: 1.5141x; 1.1881x over previous
//
#include <hip/hip_runtime.h>
#include <hip/hip_bf16.h>
#include <math.h>

// Problem constants (img 2048x2048, strides 4..64, 3 anchors/loc)
#define K_TOP 1000
#define NLEV  5
#define NSEL  5000          // 5 * 1000 candidates
#define NSLOT 5120          // 5 * 1024 slots (1024 stride per level)
#define NCH   79            // ceil(5000/64) chunks of 64 candidates
#define NP    5000          // u64 row stride of transposed mask: maskT[w*NP + i]
#define NW    80            // allocated word-rows (0..78 used)
#define ATOT  1047552
#define BBOX_CLIP_F 4.135166556742356f

// ws layout in u32 units
#define INFO1   0          // 5*4: [binstar, above, need, pad]
#define CANDCNT 32         // 5 (own 128B line)
#define EQCNT   64         // 5
#define MAXC    96         // 1 (float bits)
#define DONEC   128        // 5 (hist completion counters)
#define HIST1   256        // 5*2048 -> ends 10496
#define CANDO   10496      // 5*1024 per-level local indices -> 15616
#define EQO     15616      // u64[5*4096] = 40960 u32 -> 56576 (byte 62464 %8==0)
#define KEYS2   56576      // u64[5000] = 10000 u32 -> 66576 (byte 226304 %8==0)
#define SORTCP  66576      // u32[5120] -> 71696
#define BOXA    71696      // f32[5120][4] -> 92176
#define VALIDA  92176      // u32[5120] -> 97296
#define NBSO    97296      // f32[5120][4] -> 117776
#define AREAS   117776     // f32[5120] -> 122896
#define VALSB   122896     // u32[160] 5000-bit valid mask (byte 491584 %8==0)
#define MASKO   124080     // u64[NW*NP] (byte 496320 %16==0) -> ends 924080 u32

__device__ __forceinline__ int loff(int l){
  return (l==0)?0:(l==1)?786432:(l==2)?983040:(l==3)?1032192:1044480;
}
// monotonic uint32 key: larger float <-> larger key
__device__ __forceinline__ unsigned fmono(float x){
  unsigned b=__float_as_uint(x);
  return (b&0x80000000u)? ~b : (b|0x80000000u);
}

// inclusive block scan over 1024 threads (shuffle waves + 16-wave combine); 2 barriers.
// caller must barrier before next use of wbuf.
__device__ __forceinline__ unsigned blockscan1024(unsigned v, unsigned* wbuf, int t){
  int lane = t&63, wid = t>>6;
  #pragma unroll
  for (int d=1; d<64; d<<=1){
    unsigned u = __shfl_up(v, d, 64);
    if (lane>=d) v += u;
  }
  if (lane==63) wbuf[wid]=v;
  __syncthreads();
  if (wid==0){
    unsigned w = (lane<16)? wbuf[lane] : 0u;
    #pragma unroll
    for (int d=1; d<16; d<<=1){
      unsigned u=__shfl_up(w,d,64);
      if (lane>=d) w+=u;
    }
    if (lane<16) wbuf[lane]=w;
  }
  __syncthreads();
  unsigned off = (wid>0)? wbuf[wid-1] : 0u;
  return v+off;
}

__global__ void k_init(unsigned* ws32){
  int t=blockIdx.x*blockDim.x+threadIdx.x;
  if (t<10496) ws32[t]=0u;
  else if (t<10656) ws32[VALSB + (t-10496)]=0u;
}

// pass-1 histogram (bits 31..21): flat 512-block grid (2048 contiguous elems/block,
// each block inside ONE level since level bounds are multiples of 2048), float4 loads,
// 8x replicated LDS hist. + per-level last-block descending scan -> INFO1.
__global__ void k_hist1(const float* __restrict__ obj, unsigned* ws32){
  int b = blockIdx.x;                 // 512 blocks
  int l = (b<384)?0:(b<480)?1:(b<504)?2:(b<510)?3:4;
  unsigned* hist = ws32 + HIST1 + l*2048;
  int t = threadIdx.x;                // 256
  int rep = t & 7;
  __shared__ unsigned h[2048*8];      // 64 KiB replicated hist
  for (int i=t; i<2048*8; i+=256) h[i]=0u;
  __syncthreads();
  const float4* src = (const float4*)(obj + (size_t)b*2048);
  int nVec = (b==511)? 256 : 512;     // tail block has 1024 elems
  for (int i=t; i<nVec; i+=256){
    float4 v = src[i];
    atomicAdd(&h[(fmono(v.x)>>21)*8 + rep], 1u);
    atomicAdd(&h[(fmono(v.y)>>21)*8 + rep], 1u);
    atomicAdd(&h[(fmono(v.z)>>21)*8 + rep], 1u);
    atomicAdd(&h[(fmono(v.w)>>21)*8 + rep], 1u);
  }
  __syncthreads();
  for (int bin=t; bin<2048; bin+=256){
    unsigned v=0;
    #pragma unroll
    for (int r=0;r<8;r++) v += h[bin*8+r];
    if (v) atomicAdd(&hist[bin], v);
  }
  // per-level last-block election
  __shared__ unsigned isLast;
  __threadfence();
  if (t==0){
    unsigned nb = (l==0)?384u:(l==1)?96u:(l==2)?24u:(l==3)?6u:2u;
    unsigned old = atomicAdd(&ws32[DONEC+l],1u);
    isLast = (old == nb-1u) ? 1u : 0u;
  }
  __syncthreads();
  if (!isLast) return;
  __threadfence();
  for (int i=t; i<2048; i+=256) h[i] = atomicAdd(&hist[i],0u);  // coherent re-read
  __syncthreads();
  __shared__ unsigned psum[256];
  unsigned local=0;
  for (int r=t*8; r<t*8+8; r++) local += h[2047-r];
  psum[t]=local; __syncthreads();
  for (int s=1;s<256;s<<=1){
    unsigned v=(t>=s)?psum[t-s]:0u;
    __syncthreads();
    psum[t]+=v;
    __syncthreads();
  }
  unsigned excl=(t==0)?0u:psum[t-1];
  if (excl < K_TOP && psum[t] >= K_TOP){
    unsigned cum=excl;
    for (int r=t*8; r<t*8+8; r++){
      unsigned hv=h[2047-r];
      if (cum+hv >= K_TOP){
        ws32[INFO1+l*4+0]=(unsigned)(2047-r); // boundary bin b*
        ws32[INFO1+l*4+1]=cum;                // count in strictly greater bins
        ws32[INFO1+l*4+2]=K_TOP-cum;          // needed from bin b*
        break;
      }
      cum+=hv;
    }
  }
}

// single full scan: greater-bin -> CANDO (all top-k), boundary-bin -> EQO (u64 sort keys)
// wave-aggregated appends; level bounds & ATOT are multiples of 64 so waves never straddle.
__global__ void k_collect(const float* __restrict__ obj, unsigned* ws32){
  unsigned b0=ws32[INFO1+0], b1=ws32[INFO1+4], b2=ws32[INFO1+8],
           b3=ws32[INFO1+12], b4=ws32[INFO1+16];
  int lane = threadIdx.x & 63;
  unsigned long long lmask = (lane==0)?0ULL:(~0ULL >> (64-lane));
  unsigned long long* eq64 = (unsigned long long*)(ws32+EQO);
  for (int g = blockIdx.x*blockDim.x + threadIdx.x; g<ATOT; g += gridDim.x*blockDim.x){
    int l = (g<786432)?0:(g<983040)?1:(g<1032192)?2:(g<1044480)?3:4;
    unsigned bstar = (l==0)?b0:(l==1)?b1:(l==2)?b2:(l==3)?b3:b4;
    unsigned key = fmono(obj[g]);
    unsigned bin = key>>21;
    bool isc = bin>bstar, ise = bin==bstar;
    unsigned long long mc = __ballot(isc);
    unsigned long long me = __ballot(ise);
    if (mc){
      unsigned base=0;
      if (lane==0) base = atomicAdd(&ws32[CANDCNT+l], (unsigned)__popcll(mc));
      base = __shfl(base, 0, 64);
      if (isc){
        unsigned p = base + (unsigned)__popcll(mc & lmask);
        if (p<1024u) ws32[CANDO + l*1024 + p] = (unsigned)(g - loff(l));
      }
    }
    if (me){
      unsigned base=0;
      if (lane==0) base = atomicAdd(&ws32[EQCNT+l], (unsigned)__popcll(me));
      base = __shfl(base, 0, 64);
      if (ise){
        unsigned p = base + (unsigned)__popcll(me & lmask);
        unsigned idx = (unsigned)(g - loff(l));
        if (p<4096u) eq64[(size_t)l*4096 + p] = (((unsigned long long)(~key))<<20) | idx;
      }
    }
  }
}

// fused per-level (1024 threads, 1 block/level):
//  phase A: exact 4-level radix SELECT of the `need` smallest (m,idx) keys from the
//           boundary bin (no sort -- the set is all phase B needs).
//           key64 = (m<<20)|idx ; levels: m[20:10], m[9:0], idx[19:10], idx[9:0].
//  phase B: rank-sort the 1000 selected by key (thread t counts smaller keys via
//           broadcast LDS loop, zero barriers), then decode+clip+valid+sigmoid,
//           stable valid-partition -> KEYS2 (per-level key-ascending).
__global__ void k_tailfuse(const float* __restrict__ obj, const float* __restrict__ deltas,
                           const float* __restrict__ anchors, unsigned* ws32){
  int l = blockIdx.x, t = threadIdx.x;   // 1024 threads
  __shared__ unsigned long long sbuf[4096];   // boundary-bin keys
  __shared__ unsigned long long karr[1024];   // phase-B keys
  __shared__ unsigned hist[2048];
  __shared__ unsigned selidx[1024];
  __shared__ unsigned pfx[1024];
  __shared__ unsigned char st[4096];          // 0=TIE 1=SEL 2=REJ
  __shared__ unsigned wbuf[16];
  __shared__ unsigned sdS, scltS, sneeS, scntS, nvS;
  int off = loff(l);
  unsigned cnt = ws32[EQCNT+l]; if (cnt>4096u) cnt=4096u;
  unsigned base = ws32[CANDCNT+l];
  unsigned need = ws32[INFO1+l*4+2];
  const unsigned long long* eq = (const unsigned long long*)(ws32+EQO) + (size_t)l*4096;
  for (int i=t;i<(int)cnt;i+=1024){ sbuf[i]=eq[i]; st[i]=0; }
  if (t==0) sneeS = need;
  __syncthreads();
  // ---- phase A: 4-level radix select ----
  #pragma unroll
  for (int lev=0; lev<4; ++lev){
    int sh = (lev==0)?30:(lev==1)?20:(lev==2)?10:0;
    unsigned msk = (lev==0)?0x7FFu:0x3FFu;
    hist[2*t]=0u; hist[2*t+1]=0u;
    __syncthreads();
    for (int i=t;i<(int)cnt;i+=1024)
      if (st[i]==0) atomicAdd(&hist[(unsigned)((sbuf[i]>>sh)&msk)],1u);
    __syncthreads();
    unsigned h0=hist[2*t], h1=hist[2*t+1];
    unsigned incl = blockscan1024(h0+h1, wbuf, t);
    unsigned cumprev = incl - h0 - h1;
    unsigned needc = sneeS;
    if (cumprev < needc && needc <= cumprev+h0){ sdS=(unsigned)(2*t); scltS=cumprev; }
    else if (cumprev+h0 < needc && needc <= incl){ sdS=(unsigned)(2*t+1); scltS=cumprev+h0; }
    __syncthreads();
    unsigned dstar=sdS, clt=scltS;
    if (t==0) sneeS -= clt;
    for (int i=t;i<(int)cnt;i+=1024){
      if (st[i]==0){
        unsigned d=(unsigned)((sbuf[i]>>sh)&msk);
        st[i] = (d<dstar)?1u: (d>dstar)?2u:0u;
      }
    }
    __syncthreads();
  }
  // leftover TIE (exactly the last needed element(s)) -> SEL; compact
  if (t==0) scntS = base;
  __syncthreads();
  for (int i=t;i<(int)cnt;i+=1024)
    if (st[i]!=2u){ unsigned p=atomicAdd(&scntS,1u); if (p<1024u) selidx[p]=(unsigned)(sbuf[i]&0xFFFFFULL); }
  if (t<(int)base) selidx[t]=ws32[CANDO+l*1024+t];
  __syncthreads();
  // ---- phase B: rank-sort + decode ----
  unsigned idx_t = (t<K_TOP)? selidx[t] : 0u;
  unsigned long long mykey;
  if (t<K_TOP){
    unsigned m = ~fmono(obj[off+idx_t]);
    mykey = (((unsigned long long)m)<<20) | idx_t;
  } else mykey = ~0ULL;
  karr[t]=mykey;
  __syncthreads();
  int j = 0;
  if (t<K_TOP){
    #pragma unroll 4
    for (int u=0; u<K_TOP; ++u) j += (karr[u] < mykey) ? 1 : 0;
  }
  // j = concat position of this thread's element within the level
  unsigned valid=0u;
  unsigned long long key64=~0ULL;
  int s = (l<<10)|j;
  if (t<K_TOP){
    unsigned idx = idx_t;
    int g = off + (int)idx;
    float o = obj[g];
    const float* dd = deltas + 4*(size_t)g;
    const float* aa = anchors + 4*(size_t)g;
    float dx=dd[0], dy=dd[1], dw=dd[2], dh=dd[3];
    float a0=aa[0], a1=aa[1], a2=aa[2], a3=aa[3];
    float w = __fsub_rn(a2,a0), h = __fsub_rn(a3,a1);
    float cx = __fadd_rn(a0, __fmul_rn(0.5f,w));
    float cy = __fadd_rn(a1, __fmul_rn(0.5f,h));
    float dwc = fminf(dw, BBOX_CLIP_F);
    float dhc = fminf(dh, BBOX_CLIP_F);
    float pcx = __fadd_rn(__fmul_rn(dx,w), cx);
    float pcy = __fadd_rn(__fmul_rn(dy,h), cy);
    float pw = __fmul_rn((float)exp((double)dwc), w);
    float ph = __fmul_rn((float)exp((double)dhc), h);
    float x1 = __fsub_rn(pcx, __fmul_rn(0.5f,pw));
    float y1 = __fsub_rn(pcy, __fmul_rn(0.5f,ph));
    float x2 = __fadd_rn(pcx, __fmul_rn(0.5f,pw));
    float y2 = __fadd_rn(pcy, __fmul_rn(0.5f,ph));
    float x1c=fminf(fmaxf(x1,0.0f),2048.0f);
    float y1c=fminf(fmaxf(y1,0.0f),2048.0f);
    float x2c=fminf(fmaxf(x2,0.0f),2048.0f);
    float y2c=fminf(fmaxf(y2,0.0f),2048.0f);
    bool v = (__fsub_rn(x2c,x1c)>=0.001f) && (__fsub_rn(y2c,y1c)>=0.001f);
    float* bx = (float*)(ws32+BOXA) + 4*s;
    bx[0]=x1c; bx[1]=y1c; bx[2]=x2c; bx[3]=y2c;
    ws32[VALIDA+s] = v?1u:0u;
    valid = v?1u:0u;
    double sg = 1.0/(1.0+exp(-(double)o));
    float sc = (float)sg;
    if (sc < 0.0f) valid = 0u;
    float masked = valid? sc : -1.0f;
    unsigned sm = ~fmono(masked);
    unsigned cp = (unsigned)(l*K_TOP + j);
    key64 = ((unsigned long long)sm<<13) | cp;
    float mx = fmaxf(fmaxf(x1c,y1c),fmaxf(x2c,y2c));
    atomicMax(&ws32[MAXC], __float_as_uint(mx));
  }
  // stable partition over concat order j: valid block then invalid block == key-ascending
  if (t<K_TOP) pfx[j] = valid; 
  if (t>=K_TOP) pfx[t] = 0u;
  __syncthreads();
  unsigned incl2 = blockscan1024(pfx[t], wbuf, t);
  if (t==1023) nvS = incl2;
  pfx[t] = incl2;               // inclusive prefix at position t (== rank order)
  __syncthreads();
  if (t<K_TOP){
    unsigned inc = pfx[j];
    unsigned nv = nvS;
    unsigned pos = valid? (inc-1u) : (nv + (unsigned)j - inc);
    ((unsigned long long*)(ws32+KEYS2))[l*K_TOP + pos] = key64;
  }
}

// fused 5-way merge by rank + prep: grank via 4 binary searches (keys unique by cp),
// then write NBSO/AREAS/SORTCP/VALSB directly at the sorted position.
__global__ void k_mergeprep(unsigned* ws32){
  int l = blockIdx.x, t = threadIdx.x;  // 5 blocks x 1024
  const unsigned long long* k2 = (const unsigned long long*)(ws32+KEYS2);
  __shared__ unsigned long long sk[NLEV][K_TOP];   // 40000 B
  for (int m=0;m<NLEV;m++)
    if (t<K_TOP) sk[m][t] = k2[m*K_TOP+t];
  __syncthreads();
  if (t>=K_TOP) return;
  unsigned long long key = sk[l][t];
  int grank = t;
  #pragma unroll
  for (int m=0;m<NLEV;m++){
    if (m==l) continue;
    int lo=0, hi=K_TOP;
    while (lo<hi){ int mid=(lo+hi)>>1; if (sk[m][mid]<key) lo=mid+1; else hi=mid; }
    grank += lo;
  }
  unsigned cp = (unsigned)(key & 0x1FFFULL);
  int j = (int)cp - l*K_TOP;
  int s = (l<<10)|j;
  const float* bx = (const float*)(ws32+BOXA) + 4*s;
  float mc = __uint_as_float(ws32[MAXC]);
  float offv = __fmul_rn((float)l, __fadd_rn(mc,1.0f));
  float n0=__fadd_rn(bx[0],offv), n1=__fadd_rn(bx[1],offv);
  float n2=__fadd_rn(bx[2],offv), n3=__fadd_rn(bx[3],offv);
  float* nb = (float*)(ws32+NBSO) + 4*grank;
  nb[0]=n0; nb[1]=n1; nb[2]=n2; nb[3]=n3;
  ((float*)(ws32+AREAS))[grank] = __fmul_rn(__fsub_rn(n2,n0), __fsub_rn(n3,n1));
  ws32[SORTCP+grank] = cp;
  if (ws32[VALIDA+s]) atomicOr(&ws32[VALSB + (grank>>5)], 1u<<(grank&31));
}

// transposed suppression mask, LOWER TRIANGLE only (k_nms reads w <= chunk(i)):
// maskT[w*NP + i] bit b = IoU(i, 64w+b) > 0.7
__global__ void k_mask(unsigned* ws32){
  if (blockIdx.y > blockIdx.x) return;   // w > chunk(i): never read
  int i = blockIdx.x*64 + threadIdx.x;
  int w = blockIdx.y;
  if (i >= NSEL) return;
  const float* nbS = (const float*)(ws32+NBSO);
  const float* areaS = (const float*)(ws32+AREAS);
  unsigned long long* maskT = (unsigned long long*)(ws32+MASKO);
  float bx1=nbS[4*i], by1=nbS[4*i+1], bx2=nbS[4*i+2], by2=nbS[4*i+3];
  float ai=areaS[i];
  unsigned long long word=0ULL;
  int jbase=w*64;
  int jend = jbase+64; if (jend>NSEL) jend=NSEL;
  for (int j=jbase; j<jend; ++j){
    float iw = fmaxf(__fsub_rn(fminf(nbS[4*j+2],bx2), fmaxf(nbS[4*j+0],bx1)),0.0f);
    float ih = fmaxf(__fsub_rn(fminf(nbS[4*j+3],by2), fmaxf(nbS[4*j+1],by1)),0.0f);
    float inter=__fmul_rn(iw,ih);
    float iou=__fdiv_rn(inter, __fsub_rn(__fadd_rn(areaS[j],ai),inter));
    if (iou>0.7f) word |= (1ULL<<(j-jbase));
  }
  maskT[(size_t)w*NP + i]=word;
}

// chunk-64 gather NMS with early exit at rank>=1000 + fused output gather.
__global__ void __launch_bounds__(64) k_nms(const unsigned* __restrict__ ws32,
                                            float* __restrict__ out){
  const unsigned long long* maskT = (const unsigned long long*)(ws32+MASKO);
  const unsigned long long* validw = (const unsigned long long*)(ws32+VALSB);
  int lane = threadIdx.x;
  __shared__ unsigned long long Kb[NW];   // kept word per finished chunk
  __shared__ unsigned long long Vb[NW];   // valid words
  __shared__ unsigned ordl[K_TOP];        // kept sorted-positions (LDS)
  if (lane < NCH) Vb[lane] = validw[lane];
  __syncthreads();
  unsigned long long lower = (lane==0)?0ULL:(~0ULL >> (64-lane));
  int rank=0;
  for (int c=0;c<NCH;c++){
    int q = (c<<6) + lane;
    size_t qc = (q < NSEL)? (size_t)q : (size_t)(NSEL-1);  // clamped lanes have valid=0, never kept
    unsigned long long sup=0ULL;
    #pragma unroll 8
    for (int w=0; w<c; ++w)
      sup |= maskT[(size_t)w*NP + qc] & Kb[w];
    unsigned long long intra = maskT[(size_t)c*NP + qc];
    unsigned long long valc  = Vb[c];
    bool al = ((valc>>lane)&1ULL) && (sup==0ULL);
    unsigned long long nd = intra & lower;   // smaller-index in-chunk suppressors
    unsigned long long kept = __ballot(al);
    for (int it=0; it<96; ++it){
      bool s2 = (kept & nd) != 0ULL;
      unsigned long long nk = __ballot(al && !s2);
      if (nk==kept) break;
      kept = nk;
    }
    if ((kept>>lane)&1ULL){
      int pos = rank + (int)__popcll(kept & lower);
      if (pos < K_TOP) ordl[pos] = (unsigned)q;
    }
    rank += (int)__popcll(kept);
    if (rank >= K_TOP) break;   // exact: rank>=1000 kept are dropped by ref
    if (lane==0) Kb[c] = kept;
    __syncthreads();
  }
  __syncthreads();
  int cnt = (rank>K_TOP)?K_TOP:rank;
  for (int r=lane; r<K_TOP; r+=64){
    float4 v = make_float4(0.f,0.f,0.f,0.f);
    if (r < cnt){
      unsigned cp = ws32[SORTCP + ordl[r]];
      int l = cp/1000, j = cp - l*1000;
      int s = (l<<10)|j;
      const float* b = (const float*)(ws32+BOXA) + 4*s;
      v = make_float4(b[0],b[1],b[2],b[3]);
    }
    ((float4*)out)[r] = v;
  }
}

extern "C" void kernel_launch(void* const* d_in, const int* in_sizes, int n_in,
                              void* d_out, int out_size, void* d_ws, size_t ws_size,
                              hipStream_t stream){
  const float* obj     = (const float*)d_in[0];
  const float* deltas  = (const float*)d_in[1];
  const float* anchors = (const float*)d_in[2];
  unsigned* ws32 = (unsigned*)d_ws;
  float* out = (float*)d_out;
  (void)in_sizes; (void)n_in; (void)out_size; (void)ws_size;

  hipLaunchKernelGGL(k_init,      dim3(42),      dim3(256), 0, stream, ws32);
  hipLaunchKernelGGL(k_hist1,     dim3(512),     dim3(256), 0, stream, obj, ws32);
  hipLaunchKernelGGL(k_collect,   dim3(512),     dim3(256), 0, stream, obj, ws32);
  hipLaunchKernelGGL(k_tailfuse,  dim3(5),       dim3(1024),0, stream, obj, deltas, anchors, ws32);
  hipLaunchKernelGGL(k_mergeprep, dim3(5),       dim3(1024),0, stream, ws32);
  hipLaunchKernelGGL(k_mask,      dim3(79,79),   dim3(64),  0, stream, ws32);
  hipLaunchKernelGGL(k_nms,       dim3(1),       dim3(64),  0, stream, ws32, out);
}